// Round 7
// baseline (288.226 us; speedup 1.0000x reference)
//
#include <hip/hip_runtime.h>
#include <stdint.h>

typedef unsigned short u16;
typedef __attribute__((ext_vector_type(4))) unsigned short u16x4;
typedef __attribute__((ext_vector_type(8))) unsigned short u16x8;
typedef __attribute__((ext_vector_type(8))) __bf16 bf16x8;
typedef __attribute__((ext_vector_type(2))) _Float16 half2;
typedef __attribute__((ext_vector_type(8))) _Float16 half8;
typedef __attribute__((ext_vector_type(4))) float f32x4;

#define SEQ 2048
#define DM 1024
#define NH 16
#define DH 64
#define BATCH 4
#define MROWS (BATCH * SEQ)  // 8192

// 0.125 (= Dh^-0.5) * log2(e): folded into the Q projection so S^T comes out
// of the MFMA already in log2 units.
#define SC_LOG2E 0.18033688011112042f

__device__ __forceinline__ u16 f2bf(float f) {
    uint32_t u = __builtin_bit_cast(uint32_t, f);
    u += 0x7fffu + ((u >> 16) & 1u);   // RNE
    return (u16)(u >> 16);
}
__device__ __forceinline__ u16 f2h(float f) {
    return __builtin_bit_cast(u16, (_Float16)f);
}
__device__ __forceinline__ half2 pkrtz(float a, float b) {
    return __builtin_bit_cast(half2, __builtin_amdgcn_cvt_pkrtz(a, b));
}

__device__ __forceinline__ void load16_lds(const void* g, void* l) {
    __builtin_amdgcn_global_load_lds(
        (const __attribute__((address_space(1))) uint32_t*)(uintptr_t)g,
        (__attribute__((address_space(3))) uint32_t*)(uintptr_t)l,
        16, 0, 0);
}

// ---------------- fp32 -> bf16 convert: ALL six tensors, one launch --------
#define N4A (MROWS * DM / 4)  // 2097152
#define N4W (DM * DM / 4)     // 262144

__device__ __forceinline__ void cvt_one(const float* src, u16* dst, int i) {
    float4 v = ((const float4*)src)[i];
    u16x4 o;
    o[0] = f2bf(v.x); o[1] = f2bf(v.y); o[2] = f2bf(v.z); o[3] = f2bf(v.w);
    *(u16x4*)(dst + (size_t)i * 4) = o;
}

__global__ void cvt_all(const float* __restrict__ q, const float* __restrict__ kv,
                        const float* __restrict__ w0, const float* __restrict__ w1,
                        const float* __restrict__ w2, const float* __restrict__ w3,
                        u16* __restrict__ dq, u16* __restrict__ dkv,
                        u16* __restrict__ dw0, u16* __restrict__ dw1,
                        u16* __restrict__ dw2, u16* __restrict__ dw3) {
    int i = blockIdx.x * 256 + threadIdx.x;
    if (i < N4A) { cvt_one(q, dq, i); return; }
    i -= N4A;
    if (i < N4A) { cvt_one(kv, dkv, i); return; }
    i -= N4A;
    int s = i >> 18;            // 0..3 (N4W = 2^18)
    int l = i & (N4W - 1);
    const float* src = s == 0 ? w0 : s == 1 ? w1 : s == 2 ? w2 : w3;
    u16* dst = s == 0 ? dw0 : s == 1 ? dw1 : s == 2 ? dw2 : dw3;
    cvt_one(src, dst, l);
}

// ---------------- fused QKV projection GEMM ----------------
// 1536 blocks, 1D grid with XCD-aware decode (xcd = id%8 heuristic): all 24
// blocks sharing one m-row-block land on one XCD's L2.
// sel 0/1 (Q/K): C computed TRANSPOSED (A=weight frag) so each lane holds 4
// consecutive output features -> u16x4 stores. sel 2 (V): original
// orientation; transposed f16 store [bh][d][S] is s-vectorized via r.
__global__ __launch_bounds__(256) void qkv_gemm(const u16* __restrict__ q_bf,
                                                const u16* __restrict__ kv_bf,
                                                const u16* __restrict__ wq,
                                                const u16* __restrict__ wk,
                                                const u16* __restrict__ wv,
                                                u16* __restrict__ Qh,
                                                u16* __restrict__ Kh,
                                                u16* __restrict__ Vt) {
    __shared__ __align__(16) u16 lA[128 * 32];
    __shared__ __align__(16) u16 lB[128 * 32];
    const int t = threadIdx.x;
    const int lane = t & 63;
    const int w = t >> 6;
    const int ln = lane & 15, quad = lane >> 4;
    // XCD-aware decode: L = c + 8*(gi*24 + sel*8 + nblk), mblk = gi*8 + c
    const int L = blockIdx.x;
    const int c = L & 7;
    const int idx = L >> 3;
    const int gi = idx / 24;
    const int j = idx - gi * 24;
    const int sel = j >> 3;                   // 0=Q 1=K 2=V
    const int n0 = (j & 7) * 128;
    const int m0 = (gi * 8 + c) * 128;
    const int wm = (w >> 1) * 64, wn = (w & 1) * 64;
    const u16* A = (sel == 0) ? q_bf : kv_bf;
    const u16* B = (sel == 0) ? wq : (sel == 1 ? wk : wv);

    f32x4 acc[4][4] = {};

    for (int k0 = 0; k0 < DM; k0 += 32) {
#pragma unroll
        for (int i = 0; i < 2; ++i) {
            int cc = i * 256 + t;
            int row = cc >> 2, colq = cc & 3;
            load16_lds(A + (size_t)(m0 + row) * DM + k0 + colq * 8, &lA[cc * 8]);
            load16_lds(B + (size_t)(n0 + row) * DM + k0 + colq * 8, &lB[cc * 8]);
        }
        __syncthreads();

        bf16x8 af[4], bfr[4];
#pragma unroll
        for (int mi = 0; mi < 4; ++mi)
            af[mi] = __builtin_bit_cast(bf16x8, *(const u16x8*)&lA[(wm + mi * 16 + ln) * 32 + quad * 8]);
#pragma unroll
        for (int ni = 0; ni < 4; ++ni)
            bfr[ni] = __builtin_bit_cast(bf16x8, *(const u16x8*)&lB[(wn + ni * 16 + ln) * 32 + quad * 8]);
        if (sel == 2) {  // C[m=s][n=feat]
#pragma unroll
            for (int mi = 0; mi < 4; ++mi)
#pragma unroll
                for (int ni = 0; ni < 4; ++ni)
                    acc[mi][ni] = __builtin_amdgcn_mfma_f32_16x16x32_bf16(af[mi], bfr[ni], acc[mi][ni], 0, 0, 0);
        } else {         // C[m=feat][n=s] (transposed)
#pragma unroll
            for (int wi = 0; wi < 4; ++wi)
#pragma unroll
                for (int si = 0; si < 4; ++si)
                    acc[wi][si] = __builtin_amdgcn_mfma_f32_16x16x32_bf16(bfr[wi], af[si], acc[wi][si], 0, 0, 0);
        }
        __syncthreads();
    }

    if (sel == 2) {  // V: f16 transposed store Vt[(b*NH+h)*DH+d][S]
#pragma unroll
        for (int mi = 0; mi < 4; ++mi) {
            int rowb = m0 + wm + mi * 16 + quad * 4;
            int bb = rowb >> 11, s = rowb & 2047;
#pragma unroll
            for (int ni = 0; ni < 4; ++ni) {
                int col = n0 + wn + ni * 16 + ln;
                int h = col >> 6, d = col & 63;
                u16x4 o;
#pragma unroll
                for (int r = 0; r < 4; ++r) o[r] = f2h(acc[mi][ni][r]);
                *(u16x4*)(Vt + ((size_t)(bb * NH + h) * DH + d) * SEQ + s) = o;
            }
        }
    } else {  // Q/K: u16x4 stores (4 consecutive d); Q pre-scaled by SC_LOG2E
        u16* C = sel ? Kh : Qh;
        const float scale = sel ? 1.0f : SC_LOG2E;
#pragma unroll
        for (int wi = 0; wi < 4; ++wi) {
            int dglob = n0 + wn + wi * 16 + quad * 4;
            int h = dglob >> 6, d = dglob & 63;
#pragma unroll
            for (int si = 0; si < 4; ++si) {
                int s = m0 + wm + si * 16 + ln;
                int bb = s >> 11, srow = s & 2047;
                u16x4 o;
#pragma unroll
                for (int r = 0; r < 4; ++r) o[r] = f2bf(acc[wi][si][r] * scale);
                *(u16x4*)(C + (((size_t)((bb * NH + h) * SEQ + srow)) << 6) + d) = o;
            }
        }
    }
}

// ---------------- output projection GEMM (fp32 out, transposed C) ----------
__global__ __launch_bounds__(256) void wo_gemm(const u16* __restrict__ A,
                                               const u16* __restrict__ B,
                                               float* __restrict__ Cout) {
    __shared__ __align__(16) u16 lA[128 * 32];
    __shared__ __align__(16) u16 lB[128 * 32];
    const int t = threadIdx.x;
    const int lane = t & 63;
    const int w = t >> 6;
    const int ln = lane & 15, quad = lane >> 4;
    // XCD-aware decode: 512 blocks; mblk = gi*8 + c, nblk = idx&7
    const int L = blockIdx.x;
    const int c = L & 7;
    const int idx = L >> 3;
    const int m0 = ((idx >> 3) * 8 + c) * 128;
    const int n0 = (idx & 7) * 128;
    const int wm = (w >> 1) * 64, wn = (w & 1) * 64;

    f32x4 acc[4][4] = {};

    for (int k0 = 0; k0 < DM; k0 += 32) {
#pragma unroll
        for (int i = 0; i < 2; ++i) {
            int cc = i * 256 + t;
            int row = cc >> 2, colq = cc & 3;
            load16_lds(A + (size_t)(m0 + row) * DM + k0 + colq * 8, &lA[cc * 8]);
            load16_lds(B + (size_t)(n0 + row) * DM + k0 + colq * 8, &lB[cc * 8]);
        }
        __syncthreads();

        bf16x8 af[4], bfr[4];
#pragma unroll
        for (int mi = 0; mi < 4; ++mi)
            af[mi] = __builtin_bit_cast(bf16x8, *(const u16x8*)&lA[(wm + mi * 16 + ln) * 32 + quad * 8]);
#pragma unroll
        for (int ni = 0; ni < 4; ++ni)
            bfr[ni] = __builtin_bit_cast(bf16x8, *(const u16x8*)&lB[(wn + ni * 16 + ln) * 32 + quad * 8]);
#pragma unroll
        for (int wi = 0; wi < 4; ++wi)
#pragma unroll
            for (int si = 0; si < 4; ++si)
                acc[wi][si] = __builtin_amdgcn_mfma_f32_16x16x32_bf16(bfr[wi], af[si], acc[wi][si], 0, 0, 0);
        __syncthreads();
    }

    // C^T layout: lane holds 4 consecutive cols (features) at fixed row s
#pragma unroll
    for (int wi = 0; wi < 4; ++wi) {
        int dglob = n0 + wn + wi * 16 + quad * 4;
#pragma unroll
        for (int si = 0; si < 4; ++si) {
            int s = m0 + wm + si * 16 + ln;
            float4 o = {acc[wi][si][0], acc[wi][si][1], acc[wi][si][2], acc[wi][si][3]};
            *(float4*)&Cout[(size_t)s * DM + dglob] = o;
        }
    }
}

// ---------------- flash attention v5 (unchanged from round 6) ----------------
__global__ __launch_bounds__(256) void attn_kernel(const u16* __restrict__ Q,
                                                   const u16* __restrict__ K,
                                                   const u16* __restrict__ Vt,
                                                   u16* __restrict__ AO) {
    __shared__ __align__(16) u16 qs[128 * 64];  // [q][d] swizzled, 16 KB
    __shared__ __align__(16) u16 ks[64 * 64];   // [kv-permuted][d] swizzled, 8 KB
    __shared__ __align__(16) u16 vs[80 * 64];   // [d][kv] f16; rows 64-79 const, 10 KB

    const int t = threadIdx.x;
    const int lane = t & 63, w = t >> 6;
    const int ln = lane & 15, quad = lane >> 4;
    const int l3 = ln & 7;
    const int bi = blockIdx.x;            // 0..1023
    const int bh = bi & 63;
    const int qraw = bi >> 6;             // 0..15
    const int qtile = (bh & 1) ? (15 - qraw) : qraw;  // balance swizzle
    const int q0 = qtile * 128;
    const int qw0 = q0 + w * 32;
    const int ktmax = 2 * qtile + 1;
    const u16* Qb = Q + (size_t)bh * SEQ * DH;
    const u16* Kb = K + (size_t)bh * SEQ * DH;
    const u16* Vb = Vt + (size_t)bh * DH * SEQ;
    const int b = bh >> 4, h = bh & 15;

    const int cb = t & 7;          // staging col-block
    const int r0 = t >> 3;         // staging row base (0..31)
    const int swc = ((cb ^ (r0 & 7)) << 3);
    // K source-row permutation sigma(r0): bits [b4 b3 b2 b1 b0]->[b3 b2 b4 b1 b0]
    const int sg = ((r0 & 12) << 1) | ((r0 & 16) >> 2) | (r0 & 3);

    // const rows 64..79 of vs: row 64 = 1.0h (l-row), rest 0. Written once.
    if (t < 128) {
        int jj = t >> 3;           // 0..15
        u16 hv = (jj == 0) ? 0x3C00 : 0;
        u16x8 o = {hv, hv, hv, hv, hv, hv, hv, hv};
        *(u16x8*)&vs[((64 + jj) << 6) | (((t & 7) ^ (jj & 7)) << 3)] = o;
    }

    // prefetch Q tile + KV tile 0 into regs (K rows permuted by sigma)
    u16x8 qreg[4];
#pragma unroll
    for (int i = 0; i < 4; ++i)
        qreg[i] = *(const u16x8*)(Qb + (size_t)(q0 + r0 + i * 32) * DH + cb * 8);
    u16x8 kreg[2], vreg[2];
#pragma unroll
    for (int i = 0; i < 2; ++i) {
        kreg[i] = *(const u16x8*)(Kb + (size_t)(i * 32 + sg) * DH + cb * 8);
        vreg[i] = *(const u16x8*)(Vb + (size_t)(r0 + i * 32) * SEQ + cb * 8);
    }

    f32x4 oaccT[2][5] = {};

    for (int kt = 0; kt <= ktmax; ++kt) {
        const int kv0 = kt * 64;
        __syncthreads();  // all waves done reading previous tile
        if (kt == 0) {
#pragma unroll
            for (int i = 0; i < 4; ++i)
                *(u16x8*)&qs[((r0 + i * 32) << 6) | swc] = qreg[i];
        }
#pragma unroll
        for (int i = 0; i < 2; ++i) {
            *(u16x8*)&ks[((r0 + i * 32) << 6) | swc] = kreg[i];
            *(u16x8*)&vs[((r0 + i * 32) << 6) | swc] = vreg[i];
        }
        __syncthreads();  // tile published
        if (kt < ktmax) {
            const int kvn = kv0 + 64;
#pragma unroll
            for (int i = 0; i < 2; ++i) {
                kreg[i] = *(const u16x8*)(Kb + (size_t)(kvn + i * 32 + sg) * DH + cb * 8);
                vreg[i] = *(const u16x8*)(Vb + (size_t)(r0 + i * 32) * SEQ + kvn + cb * 8);
            }
        }

        if (kv0 >= qw0 + 32) continue;  // wave-uniform; barriers already done

        // ---- S^T = K Q^T : C[m=permuted kv][n=q] ----
        f32x4 st[2][4] = {};
#pragma unroll
        for (int half = 0; half < 2; ++half) {
            const int swz = (((half * 4 + quad) ^ l3) << 3);
            bf16x8 qf0 = __builtin_bit_cast(bf16x8, *(const u16x8*)&qs[((w * 32 + ln) << 6) | swz]);
            bf16x8 qf1 = __builtin_bit_cast(bf16x8, *(const u16x8*)&qs[((w * 32 + 16 + ln) << 6) | swz]);
#pragma unroll
            for (int ms = 0; ms < 4; ++ms) {
                bf16x8 kf = __builtin_bit_cast(bf16x8, *(const u16x8*)&ks[((ms * 16 + ln) << 6) | swz]);
                st[0][ms] = __builtin_amdgcn_mfma_f32_16x16x32_bf16(kf, qf0, st[0][ms], 0, 0, 0);
                st[1][ms] = __builtin_amdgcn_mfma_f32_16x16x32_bf16(kf, qf1, st[1][ms], 0, 0, 0);
            }
        }

        // ---- P = exp2(S^T); lane's (ms,r) sits at true kv =
        //      kv0 + (ms>>1)*32 + quad*8 + (ms&1)*4 + r ----
        half8 pf[2][2];
#pragma unroll
        for (int qt2 = 0; qt2 < 2; ++qt2) {
            const int qbase = qw0 + qt2 * 16;       // lane's q = qbase + ln
            if (kv0 + 63 > qbase) {                 // diagonal tile (wave-uniform)
                const int relq = qbase + ln - kv0 - quad * 8;
#pragma unroll
                for (int ms = 0; ms < 4; ++ms)
#pragma unroll
                    for (int r = 0; r < 4; ++r)
                        if ((ms >> 1) * 32 + (ms & 1) * 4 + r > relq)
                            st[qt2][ms][r] = -3e38f;
            }
#pragma unroll
            for (int cc = 0; cc < 2; ++cc) {
                half2 p0 = pkrtz(__builtin_amdgcn_exp2f(st[qt2][2 * cc][0]),
                                 __builtin_amdgcn_exp2f(st[qt2][2 * cc][1]));
                half2 p1 = pkrtz(__builtin_amdgcn_exp2f(st[qt2][2 * cc][2]),
                                 __builtin_amdgcn_exp2f(st[qt2][2 * cc][3]));
                half2 p2 = pkrtz(__builtin_amdgcn_exp2f(st[qt2][2 * cc + 1][0]),
                                 __builtin_amdgcn_exp2f(st[qt2][2 * cc + 1][1]));
                half2 p3 = pkrtz(__builtin_amdgcn_exp2f(st[qt2][2 * cc + 1][2]),
                                 __builtin_amdgcn_exp2f(st[qt2][2 * cc + 1][3]));
                half8 v;
                v[0] = p0[0]; v[1] = p0[1]; v[2] = p1[0]; v[3] = p1[1];
                v[4] = p2[0]; v[5] = p2[1]; v[6] = p3[0]; v[7] = p3[1];
                pf[qt2][cc] = v;
            }
        }

        // ---- O^T += V^T P^T : 16x16x32_f16; nd=4 accumulates l (ones-row) --
#pragma unroll
        for (int cc = 0; cc < 2; ++cc) {
            const int off = (((cc * 4 + quad) ^ l3) << 3);
#pragma unroll
            for (int nd = 0; nd < 5; ++nd) {
                half8 vf = __builtin_bit_cast(half8, *(const u16x8*)&vs[((nd * 16 + ln) << 6) | off]);
                oaccT[0][nd] = __builtin_amdgcn_mfma_f32_16x16x32_f16(vf, pf[0][cc], oaccT[0][nd], 0, 0, 0);
                oaccT[1][nd] = __builtin_amdgcn_mfma_f32_16x16x32_f16(vf, pf[1][cc], oaccT[1][nd], 0, 0, 0);
            }
        }
    }

    // epilogue: O^T rows = d, cols = q (= ln); l in quad 0's oaccT[qt2][4][0]
#pragma unroll
    for (int qt2 = 0; qt2 < 2; ++qt2) {
        float lv = __shfl(oaccT[qt2][4][0], ln, 64);
        float linv = 1.0f / lv;
        int q = q0 + w * 32 + qt2 * 16 + ln;
        size_t base = ((size_t)(b * SEQ + q) * DM) + h * DH + quad * 4;
#pragma unroll
        for (int nd = 0; nd < 4; ++nd) {
            u16x4 o;
#pragma unroll
            for (int r = 0; r < 4; ++r) o[r] = f2bf(oaccT[qt2][nd][r] * linv);
            *(u16x4*)&AO[base + nd * 16] = o;
        }
    }
}

// ---------------- launch ----------------
extern "C" void kernel_launch(void* const* d_in, const int* in_sizes, int n_in,
                              void* d_out, int out_size, void* d_ws, size_t ws_size,
                              hipStream_t stream) {
    const float* query = (const float*)d_in[0];
    const float* key_value = (const float*)d_in[1];
    const float* Wq = (const float*)d_in[2];
    const float* Wk = (const float*)d_in[3];
    const float* Wv = (const float*)d_in[4];
    const float* Wo = (const float*)d_in[5];
    float* out = (float*)d_out;

    char* ws = (char*)d_ws;
    const size_t SZ_ACT = (size_t)MROWS * DM * 2;  // 16 MiB
    const size_t SZ_W = (size_t)DM * DM * 2;       // 2 MiB
    u16* q_bf  = (u16*)(ws + 0);
    u16* kv_bf = (u16*)(ws + SZ_ACT);
    u16* wq_bf = (u16*)(ws + 2 * SZ_ACT);
    u16* wk_bf = (u16*)(ws + 2 * SZ_ACT + SZ_W);
    u16* wv_bf = (u16*)(ws + 2 * SZ_ACT + 2 * SZ_W);
    u16* wo_bf = (u16*)(ws + 2 * SZ_ACT + 3 * SZ_W);
    u16* Qh    = (u16*)(ws + 2 * SZ_ACT + 4 * SZ_W);              // [B,H,S,Dh] bf16 (pre-scaled)
    u16* Kh    = (u16*)(ws + 2 * SZ_ACT + 4 * SZ_W + SZ_ACT);     // [B,H,S,Dh] bf16
    u16* Vt    = (u16*)(ws + 2 * SZ_ACT + 4 * SZ_W + 2 * SZ_ACT); // [bh][64][S] f16
    u16* AOb   = q_bf;   // q_bf dead after Q projection

    const int n4_total = 2 * N4A + 4 * N4W;  // 5,242,880
    cvt_all<<<n4_total / 256, 256, 0, stream>>>(query, key_value, Wq, Wk, Wv, Wo,
                                                q_bf, kv_bf, wq_bf, wk_bf, wv_bf, wo_bf);

    qkv_gemm<<<1536, 256, 0, stream>>>(q_bf, kv_bf, wq_bf, wk_bf, wv_bf, Qh, Kh, Vt);

    attn_kernel<<<1024, 256, 0, stream>>>(Qh, Kh, Vt, AOb);

    wo_gemm<<<512, 256, 0, stream>>>(AOb, wo_bf, out);
}